// Round 16
// baseline (203.153 us; speedup 1.0000x reference)
//
#include <hip/hip_runtime.h>
#include <hip/hip_bf16.h>
#include <hip/hip_fp16.h>
#include <cstdint>

typedef __attribute__((ext_vector_type(4))) float f32x4;
typedef __attribute__((ext_vector_type(8))) short s16x8;

#define DEVI static __device__ __forceinline__

constexpr int Bc = 8, Tc = 2048, Sc = 8, Dc = 256;
constexpr int Mc = Bc * Tc * Sc;  // 131072 rows

// plain-cast f32->bf16 (RNE): compiler packs pairs into v_cvt_pk_bf16_f32
DEVI unsigned short f2bf(float x) {
  return __bfloat16_as_ushort(__float2bfloat16(x));
}

DEVI s16x8 cvt8(f32x4 a, f32x4 b) {
  s16x8 o;
  o[0] = (short)f2bf(a[0]); o[1] = (short)f2bf(a[1]);
  o[2] = (short)f2bf(a[2]); o[3] = (short)f2bf(a[3]);
  o[4] = (short)f2bf(b[0]); o[5] = (short)f2bf(b[1]);
  o[6] = (short)f2bf(b[2]); o[7] = (short)f2bf(b[3]);
  return o;
}

DEVI f32x4 mfma16(s16x8 a, s16x8 b, f32x4 c) {
  return __builtin_amdgcn_mfma_f32_16x16x32_bf16(a, b, c, 0, 0, 0);
}

// async global->LDS, 16B per lane (dest must be wave-uniform base + lane*16)
DEVI void gld16(const void* g, void* l) {
  __builtin_amdgcn_global_load_lds(
      (const __attribute__((address_space(1))) unsigned int*)g,
      (__attribute__((address_space(3))) unsigned int*)l, 16, 0, 0);
}

// ---------------- weight transpose+convert (both W in one kernel) ----------------
__global__ void cvtW_k(const float* __restrict__ Win, const float* __restrict__ Wout,
                       unsigned short* __restrict__ wtin, unsigned short* __restrict__ wtout) {
  int tid = blockIdx.x * blockDim.x + threadIdx.x;
  if (tid < 512 * 256) {
    int c = tid >> 8, r = tid & 255;
    wtin[tid] = f2bf(Win[r * 512 + c]);
  } else {
    int t = tid - 512 * 256;
    int c = t >> 8, r = t & 255;
    wtout[t] = f2bf(Wout[r * 256 + c]);
  }
}

// ---------------- fused convert + GEMM1 + activation + scan ----------------
// r15 structure + in-kernel f32->bf16 A-conversion (cvt_x kernel DELETED).
// Reg-staging with FULL-CHUNK cover (the r3-r6 failures had ~200cy cover):
//   after barrier of chunk ch:   issue 8 f32x4 loads for chunk ch+2 -> pa
//   end of chunk ch+1 (pre-bar): convert pa -> ds_write As[(ch+2)&1]
// Load->use distance ~1 chunk (~1900 cyc) >> HBM latency. Single pa set
// (consumed before re-issued, around the barrier). +32 VGPR.
__global__ __launch_bounds__(512, 4) void g1scan_k(
    const float* __restrict__ x,             // [M][256] f32
    const unsigned short* __restrict__ wt,   // [512][256] bf16 = W_in^T
    const float* __restrict__ bias,          // [512]
    unsigned short* __restrict__ yb)         // [M][256] bf16
{
  __shared__ unsigned short As[2][8 * 64 * 32];   // 2 x 32 KB; [buf][kf][row64][32]
  __shared__ float segA[2][4][32], segB[2][4][32]; // 2 KB wave-segment pairs

  int bid = blockIdx.x;
  int lb = (bid & 7) * 64 + (bid >> 3);           // XCD x owns batch b = x
  int b = lb >> 6, s = (lb >> 3) & 7, dq = lb & 7;
  int tid = threadIdx.x;
  int lane = tid & 63, wave = tid >> 6;
  int rg = wave >> 1, cg = wave & 1;              // 4 t-row groups x 2 col groups
  int lo = lane & 15, hi = lane >> 4;

  const short* wsrc = (const short*)wt;
  size_t rowbase = (size_t)b * 16384 + s;         // global row = rowbase + t*8

  int cl = cg * 16 + lo;                          // d-local col in [0,32)
  int kg = hi * 8;

  // ---- W fragments: global -> registers (one-time, L2-resident weights) ----
  s16x8 bGr[8], bCr[8];
  #pragma unroll
  for (int kf = 0; kf < 8; ++kf) {
    bGr[kf] = *(const s16x8*)(wsrc + (size_t)(dq * 32 + cl) * 256 + kf * 32 + kg);
    bCr[kf] = *(const s16x8*)(wsrc + (size_t)(256 + dq * 32 + cl) * 256 + kf * 32 + kg);
  }
  float bg = bias[dq * 32 + cl];
  float bc = bias[256 + dq * 32 + cl];

  // ---- reg-staging geometry: chunk = 64 rows x 256 K bf16 = 2048 x 16B LDS ----
  // j = q*512+tid -> kf = j>>8, row = (j&255)>>2, cc = j&3; LDS short-off = j*8.
  // f32 source: 32B (two f32x4) at x[row][kf*32 + cc*8].
  const float* pF[4];
  int ldso[4];
  #pragma unroll
  for (int q = 0; q < 4; ++q) {
    int j = q * 512 + tid;
    int kf = j >> 8, rem = j & 255, r = rem >> 2, cc = j & 3;
    pF[q] = x + (rowbase + (size_t)r * 8) * 256 + kf * 32 + cc * 8;
    ldso[q] = j * 8;
  }
  const size_t ASTRIDE = (size_t)64 * 8 * 256;    // elems per 64-t chunk

  f32x4 pa[4][2];
  auto LDF = [&]() {                               // issue loads, advance pointers
    #pragma unroll
    for (int q = 0; q < 4; ++q) {
      pa[q][0] = *(const f32x4*)(pF[q]);
      pa[q][1] = *(const f32x4*)(pF[q] + 4);
      pF[q] += ASTRIDE;
    }
  };
  auto WRF = [&](int buf) {                        // convert + write (waits loads)
    #pragma unroll
    for (int q = 0; q < 4; ++q)
      *(s16x8*)((unsigned short*)As[buf] + ldso[q]) = cvt8(pa[q][0], pa[q][1]);
  };

  // prologue: chunk0 -> As[0] (one-time latency stall), chunk1 loads in flight
  LDF();
  WRF(0);
  LDF();
  float stt = 0.f;   // block scan carry (identical across all threads of same d)
  __syncthreads();   // As[0] visible

  for (int ch = 0; ch < 32; ++ch) {
    int cur = ch & 1;
    const unsigned short* Ab = (const unsigned short*)As[cur];

    // ---- GEMM: this thread ends with t = ch*64 + rg*16 + hi*4 + [0,4), d = cl ----
    f32x4 accG = {}, accC = {};
    #pragma unroll
    for (int kf = 0; kf < 8; ++kf) {
      s16x8 aF = *(const s16x8*)(Ab + kf * 2048 + (rg * 16 + lo) * 32 + kg);
      accG = mfma16(aF, bGr[kf], accG);
      accC = mfma16(aF, bCr[kf], accC);
    }

    // ---- activation in-register (rcp instead of div) ----
    float av[4], bv[4];
    #pragma unroll
    for (int r = 0; r < 4; ++r) {
      float g = accG[r] + bg;
      float c = accC[r] + bc;
      float eg = __expf(-g);
      float alpha = __builtin_amdgcn_rcpf(1.f + eg);
      float e2 = __expf(2.f * c);
      float th = 1.f - 2.f * __builtin_amdgcn_rcpf(e2 + 1.f);  // tanh(c)
      av[r] = 1.f - alpha;
      bv[r] = alpha * th;
    }

    // ---- per-thread compose over its 4 t-steps ----
    float iA = av[0], iB = bv[0];
    #pragma unroll
    for (int r = 1; r < 4; ++r) { iA = iA * av[r]; iB = fmaf(av[r], iB, bv[r]); }

    // ---- in-wave inclusive prefix over hi (4 groups) ----
    {
      float tA = __shfl_up(iA, 16), tB = __shfl_up(iB, 16);
      float nA = tA * iA, nB = fmaf(iA, tB, iB);
      if (hi >= 1) { iA = nA; iB = nB; }
      tA = __shfl_up(iA, 32); tB = __shfl_up(iB, 32);
      nA = tA * iA; nB = fmaf(iA, tB, iB);
      if (hi >= 2) { iA = nA; iB = nB; }
    }
    float eA = __shfl_up(iA, 16), eB = __shfl_up(iB, 16);
    if (hi == 0) { eA = 1.f; eB = 0.f; }
    if (hi == 3) { segA[cur][rg][cl] = iA; segB[cur][rg][cl] = iB; }

    // ---- convert + write chunk ch+1's A data (loads issued last chunk) ----
    if (ch + 1 < 32) WRF(cur ^ 1);

    __syncthreads();   // THE barrier: As dbuf + segs visible

    // ---- issue chunk ch+2 f32 loads (consumed at END of next chunk) ----
    if (ch + 2 < 32) LDF();

    // ---- cross-wave walk over 4 rg segments (redundant, identical per d) ----
    float run = stt, s_w = stt;
    #pragma unroll
    for (int r2 = 0; r2 < 4; ++r2) {
      if (r2 == rg) s_w = run;
      run = fmaf(segA[cur][r2][cl], run, segB[cur][r2][cl]);
    }
    stt = run;                            // carry into next chunk

    // ---- apply: start = excl-wave o carry, then own 4 steps + store ----
    float sv = fmaf(eA, s_w, eB);
    size_t ybase = (rowbase + (size_t)(ch * 64 + rg * 16 + hi * 4) * 8) * 256 + dq * 32 + cl;
    #pragma unroll
    for (int u = 0; u < 4; ++u) {
      sv = fmaf(av[u], sv, bv[u]);
      yb[ybase + (size_t)u * 8 * 256] = f2bf(sv);
    }
  }
}

// ---------------- GEMM2: out = y@W_out + b_out ----------------
// BK=64 as two [128][32] sub-panels. grid 2048 = 1024 mtiles x 2 ctiles.
__global__ __launch_bounds__(256, 2) void gemm2_k(
    const unsigned short* __restrict__ yb,   // [M][256] bf16
    const unsigned short* __restrict__ wt,   // [256][256] bf16 = W_out^T
    const float* __restrict__ bias,          // [256]
    float* __restrict__ out)
{
  __shared__ unsigned short As[2][2][128 * 32];
  __shared__ unsigned short Bs[2][2][128 * 32];

  int bid = blockIdx.x;
  int swz = (bid & 7) * 256 + (bid >> 3);
  int mtile = swz >> 1, ctile = swz & 1;
  int tid = threadIdx.x;
  int lane = tid & 63, wave = tid >> 6;
  int wr = wave >> 1, wc = wave & 1;

  const short* ys = (const short*)yb;
  const short* wsrc = (const short*)wt;

  auto STAGE = [&](int buf, int k0) {
    unsigned short* Ad = &As[buf][0][0];
    unsigned short* Bd = &Bs[buf][0][0];
    #pragma unroll
    for (int q = 0; q < 4; ++q) {
      int j = q * 256 + tid;
      int p = j >> 9, r = (j >> 2) & 127, cc = j & 3;
      int koff = k0 + p * 32 + cc * 8;
      gld16(ys + (size_t)(mtile * 128 + r) * 256 + koff, Ad + (size_t)j * 8);
      gld16(wsrc + (size_t)(ctile * 128 + r) * 256 + koff, Bd + (size_t)j * 8);
    }
  };

  f32x4 acc[4][4] = {};

  STAGE(0, 0);
  __syncthreads();
  #pragma unroll
  for (int kk = 0; kk < 4; ++kk) {
    int cur = kk & 1;
    if (kk < 3) STAGE(cur ^ 1, (kk + 1) * 64);
    int kg = (lane >> 4) * 8;
    #pragma unroll
    for (int ks = 0; ks < 2; ++ks) {
      s16x8 aF[4], bF[4];
      #pragma unroll
      for (int mf = 0; mf < 4; ++mf)
        aF[mf] = *(const s16x8*)&As[cur][ks][(wr * 64 + mf * 16 + (lane & 15)) * 32 + kg];
      #pragma unroll
      for (int nf = 0; nf < 4; ++nf)
        bF[nf] = *(const s16x8*)&Bs[cur][ks][(wc * 64 + nf * 16 + (lane & 15)) * 32 + kg];
      #pragma unroll
      for (int mf = 0; mf < 4; ++mf)
        #pragma unroll
        for (int nf = 0; nf < 4; ++nf)
          acc[mf][nf] = mfma16(aF[mf], bF[nf], acc[mf][nf]);
    }
    if (kk < 3) __syncthreads();
  }

  int orow0 = mtile * 128 + wr * 64 + (lane >> 4) * 4;
  #pragma unroll
  for (int nf = 0; nf < 4; ++nf) {
    int col = ctile * 128 + wc * 64 + nf * 16 + (lane & 15);
    float bo = bias[col];
    #pragma unroll
    for (int mf = 0; mf < 4; ++mf) {
      #pragma unroll
      for (int r = 0; r < 4; ++r) {
        int row = orow0 + mf * 16 + r;
        out[(size_t)row * 256 + col] = acc[mf][nf][r] + bo;
      }
    }
  }
}

// ---------------- host ----------------
extern "C" void kernel_launch(void* const* d_in, const int* in_sizes, int n_in,
                              void* d_out, int out_size, void* d_ws, size_t ws_size,
                              hipStream_t stream)
{
  const float* x    = (const float*)d_in[0];
  const float* Win  = (const float*)d_in[1];
  const float* bin  = (const float*)d_in[2];
  const float* Wout = (const float*)d_in[3];
  const float* bout = (const float*)d_in[4];
  float* out = (float*)d_out;
  char* ws = (char*)d_ws;

  // ws layout: Wt_in (256 KiB) | Wt_out (128 KiB) | yb (64 MiB)
  unsigned short* wtin  = (unsigned short*)(ws);
  unsigned short* wtout = (unsigned short*)(ws + 262144);
  unsigned short* yb    = (unsigned short*)(ws + 393216);

  cvtW_k<<<768, 256, 0, stream>>>(Win, Wout, wtin, wtout);
  g1scan_k<<<512, 512, 0, stream>>>(x, wtin, bin, yb);
  gemm2_k<<<2048, 256, 0, stream>>>(yb, wtout, bout, out);
}

// Round 17
// 198.295 us; speedup vs baseline: 1.0245x; 1.0245x over previous
//
#include <hip/hip_runtime.h>
#include <hip/hip_bf16.h>
#include <hip/hip_fp16.h>
#include <cstdint>

typedef __attribute__((ext_vector_type(4))) float f32x4;
typedef __attribute__((ext_vector_type(8))) short s16x8;

#define DEVI static __device__ __forceinline__

constexpr int Bc = 8, Tc = 2048, Sc = 8, Dc = 256;
constexpr int Mc = Bc * Tc * Sc;  // 131072 rows

// plain-cast f32->bf16 (RNE): compiler packs pairs into v_cvt_pk_bf16_f32
DEVI unsigned short f2bf(float x) {
  return __bfloat16_as_ushort(__float2bfloat16(x));
}

DEVI s16x8 cvt8(f32x4 a, f32x4 b) {
  s16x8 o;
  o[0] = (short)f2bf(a[0]); o[1] = (short)f2bf(a[1]);
  o[2] = (short)f2bf(a[2]); o[3] = (short)f2bf(a[3]);
  o[4] = (short)f2bf(b[0]); o[5] = (short)f2bf(b[1]);
  o[6] = (short)f2bf(b[2]); o[7] = (short)f2bf(b[3]);
  return o;
}

DEVI f32x4 mfma16(s16x8 a, s16x8 b, f32x4 c) {
  return __builtin_amdgcn_mfma_f32_16x16x32_bf16(a, b, c, 0, 0, 0);
}

// async global->LDS, 16B per lane (dest must be wave-uniform base + lane*16)
DEVI void gld16(const void* g, void* l) {
  __builtin_amdgcn_global_load_lds(
      (const __attribute__((address_space(1))) unsigned int*)g,
      (__attribute__((address_space(3))) unsigned int*)l, 16, 0, 0);
}

// ---------------- weight transpose+convert (both W in one kernel) ----------------
__global__ void cvtW_k(const float* __restrict__ Win, const float* __restrict__ Wout,
                       unsigned short* __restrict__ wtin, unsigned short* __restrict__ wtout) {
  int tid = blockIdx.x * blockDim.x + threadIdx.x;
  if (tid < 512 * 256) {
    int c = tid >> 8, r = tid & 255;
    wtin[tid] = f2bf(Win[r * 512 + c]);
  } else {
    int t = tid - 512 * 256;
    int c = t >> 8, r = t & 255;
    wtout[t] = f2bf(Wout[r * 256 + c]);
  }
}

// ---------------- fused convert + GEMM1 + activation + scan ----------------
// r16 structure with the regalloc fix: __launch_bounds__(512,2) (r16's (512,4)
// capped VGPR at 64 -> pa[4][2] spilled to scratch: VGPR_Count 64, WRITE_SIZE
// +24MB, 177us. LDS 66.5KB caps at 2 blocks/CU regardless, so (512,2) loses
// nothing and restores the 128-VGPR budget).
// Reg-staging with FULL-CHUNK cover:
//   after barrier of chunk ch:   issue 8 f32x4 loads for chunk ch+2 -> pa
//   end of chunk ch+1 (pre-bar): convert pa -> ds_write As[(ch+2)&1]
__global__ __launch_bounds__(512, 2) void g1scan_k(
    const float* __restrict__ x,             // [M][256] f32
    const unsigned short* __restrict__ wt,   // [512][256] bf16 = W_in^T
    const float* __restrict__ bias,          // [512]
    unsigned short* __restrict__ yb)         // [M][256] bf16
{
  __shared__ unsigned short As[2][8 * 64 * 32];   // 2 x 32 KB; [buf][kf][row64][32]
  __shared__ float segA[2][4][32], segB[2][4][32]; // 2 KB wave-segment pairs

  int bid = blockIdx.x;
  int lb = (bid & 7) * 64 + (bid >> 3);           // XCD x owns batch b = x
  int b = lb >> 6, s = (lb >> 3) & 7, dq = lb & 7;
  int tid = threadIdx.x;
  int lane = tid & 63, wave = tid >> 6;
  int rg = wave >> 1, cg = wave & 1;              // 4 t-row groups x 2 col groups
  int lo = lane & 15, hi = lane >> 4;

  const short* wsrc = (const short*)wt;
  size_t rowbase = (size_t)b * 16384 + s;         // global row = rowbase + t*8

  int cl = cg * 16 + lo;                          // d-local col in [0,32)
  int kg = hi * 8;

  // ---- W fragments: global -> registers (one-time, L2-resident weights) ----
  s16x8 bGr[8], bCr[8];
  #pragma unroll
  for (int kf = 0; kf < 8; ++kf) {
    bGr[kf] = *(const s16x8*)(wsrc + (size_t)(dq * 32 + cl) * 256 + kf * 32 + kg);
    bCr[kf] = *(const s16x8*)(wsrc + (size_t)(256 + dq * 32 + cl) * 256 + kf * 32 + kg);
  }
  float bg = bias[dq * 32 + cl];
  float bc = bias[256 + dq * 32 + cl];

  // ---- reg-staging geometry: chunk = 64 rows x 256 K bf16 = 2048 x 16B LDS ----
  // j = q*512+tid -> kf = j>>8, row = (j&255)>>2, cc = j&3; LDS short-off = j*8.
  const float* pF[4];
  int ldso[4];
  #pragma unroll
  for (int q = 0; q < 4; ++q) {
    int j = q * 512 + tid;
    int kf = j >> 8, rem = j & 255, r = rem >> 2, cc = j & 3;
    pF[q] = x + (rowbase + (size_t)r * 8) * 256 + kf * 32 + cc * 8;
    ldso[q] = j * 8;
  }
  const size_t ASTRIDE = (size_t)64 * 8 * 256;    // elems per 64-t chunk

  f32x4 pa[4][2];
  auto LDF = [&]() {                               // issue loads, advance pointers
    #pragma unroll
    for (int q = 0; q < 4; ++q) {
      pa[q][0] = *(const f32x4*)(pF[q]);
      pa[q][1] = *(const f32x4*)(pF[q] + 4);
      pF[q] += ASTRIDE;
    }
  };
  auto WRF = [&](int buf) {                        // convert + write (waits loads)
    #pragma unroll
    for (int q = 0; q < 4; ++q)
      *(s16x8*)((unsigned short*)As[buf] + ldso[q]) = cvt8(pa[q][0], pa[q][1]);
  };

  // prologue: chunk0 -> As[0] (one-time latency stall), chunk1 loads in flight
  LDF();
  WRF(0);
  LDF();
  float stt = 0.f;   // block scan carry (identical across all threads of same d)
  __syncthreads();   // As[0] visible

  for (int ch = 0; ch < 32; ++ch) {
    int cur = ch & 1;
    const unsigned short* Ab = (const unsigned short*)As[cur];

    // ---- GEMM: this thread ends with t = ch*64 + rg*16 + hi*4 + [0,4), d = cl ----
    f32x4 accG = {}, accC = {};
    #pragma unroll
    for (int kf = 0; kf < 8; ++kf) {
      s16x8 aF = *(const s16x8*)(Ab + kf * 2048 + (rg * 16 + lo) * 32 + kg);
      accG = mfma16(aF, bGr[kf], accG);
      accC = mfma16(aF, bCr[kf], accC);
    }

    // ---- activation in-register (rcp instead of div) ----
    float av[4], bv[4];
    #pragma unroll
    for (int r = 0; r < 4; ++r) {
      float g = accG[r] + bg;
      float c = accC[r] + bc;
      float eg = __expf(-g);
      float alpha = __builtin_amdgcn_rcpf(1.f + eg);
      float e2 = __expf(2.f * c);
      float th = 1.f - 2.f * __builtin_amdgcn_rcpf(e2 + 1.f);  // tanh(c)
      av[r] = 1.f - alpha;
      bv[r] = alpha * th;
    }

    // ---- per-thread compose over its 4 t-steps ----
    float iA = av[0], iB = bv[0];
    #pragma unroll
    for (int r = 1; r < 4; ++r) { iA = iA * av[r]; iB = fmaf(av[r], iB, bv[r]); }

    // ---- in-wave inclusive prefix over hi (4 groups) ----
    {
      float tA = __shfl_up(iA, 16), tB = __shfl_up(iB, 16);
      float nA = tA * iA, nB = fmaf(iA, tB, iB);
      if (hi >= 1) { iA = nA; iB = nB; }
      tA = __shfl_up(iA, 32); tB = __shfl_up(iB, 32);
      nA = tA * iA; nB = fmaf(iA, tB, iB);
      if (hi >= 2) { iA = nA; iB = nB; }
    }
    float eA = __shfl_up(iA, 16), eB = __shfl_up(iB, 16);
    if (hi == 0) { eA = 1.f; eB = 0.f; }
    if (hi == 3) { segA[cur][rg][cl] = iA; segB[cur][rg][cl] = iB; }

    // ---- convert + write chunk ch+1's A data (loads issued last chunk) ----
    if (ch + 1 < 32) WRF(cur ^ 1);

    __syncthreads();   // THE barrier: As dbuf + segs visible

    // ---- issue chunk ch+2 f32 loads (consumed at END of next chunk) ----
    if (ch + 2 < 32) LDF();

    // ---- cross-wave walk over 4 rg segments (redundant, identical per d) ----
    float run = stt, s_w = stt;
    #pragma unroll
    for (int r2 = 0; r2 < 4; ++r2) {
      if (r2 == rg) s_w = run;
      run = fmaf(segA[cur][r2][cl], run, segB[cur][r2][cl]);
    }
    stt = run;                            // carry into next chunk

    // ---- apply: start = excl-wave o carry, then own 4 steps + store ----
    float sv = fmaf(eA, s_w, eB);
    size_t ybase = (rowbase + (size_t)(ch * 64 + rg * 16 + hi * 4) * 8) * 256 + dq * 32 + cl;
    #pragma unroll
    for (int u = 0; u < 4; ++u) {
      sv = fmaf(av[u], sv, bv[u]);
      yb[ybase + (size_t)u * 8 * 256] = f2bf(sv);
    }
  }
}

// ---------------- GEMM2: out = y@W_out + b_out ----------------
// BK=64 as two [128][32] sub-panels. grid 2048 = 1024 mtiles x 2 ctiles.
__global__ __launch_bounds__(256, 2) void gemm2_k(
    const unsigned short* __restrict__ yb,   // [M][256] bf16
    const unsigned short* __restrict__ wt,   // [256][256] bf16 = W_out^T
    const float* __restrict__ bias,          // [256]
    float* __restrict__ out)
{
  __shared__ unsigned short As[2][2][128 * 32];
  __shared__ unsigned short Bs[2][2][128 * 32];

  int bid = blockIdx.x;
  int swz = (bid & 7) * 256 + (bid >> 3);
  int mtile = swz >> 1, ctile = swz & 1;
  int tid = threadIdx.x;
  int lane = tid & 63, wave = tid >> 6;
  int wr = wave >> 1, wc = wave & 1;

  const short* ys = (const short*)yb;
  const short* wsrc = (const short*)wt;

  auto STAGE = [&](int buf, int k0) {
    unsigned short* Ad = &As[buf][0][0];
    unsigned short* Bd = &Bs[buf][0][0];
    #pragma unroll
    for (int q = 0; q < 4; ++q) {
      int j = q * 256 + tid;
      int p = j >> 9, r = (j >> 2) & 127, cc = j & 3;
      int koff = k0 + p * 32 + cc * 8;
      gld16(ys + (size_t)(mtile * 128 + r) * 256 + koff, Ad + (size_t)j * 8);
      gld16(wsrc + (size_t)(ctile * 128 + r) * 256 + koff, Bd + (size_t)j * 8);
    }
  };

  f32x4 acc[4][4] = {};

  STAGE(0, 0);
  __syncthreads();
  #pragma unroll
  for (int kk = 0; kk < 4; ++kk) {
    int cur = kk & 1;
    if (kk < 3) STAGE(cur ^ 1, (kk + 1) * 64);
    int kg = (lane >> 4) * 8;
    #pragma unroll
    for (int ks = 0; ks < 2; ++ks) {
      s16x8 aF[4], bF[4];
      #pragma unroll
      for (int mf = 0; mf < 4; ++mf)
        aF[mf] = *(const s16x8*)&As[cur][ks][(wr * 64 + mf * 16 + (lane & 15)) * 32 + kg];
      #pragma unroll
      for (int nf = 0; nf < 4; ++nf)
        bF[nf] = *(const s16x8*)&Bs[cur][ks][(wc * 64 + nf * 16 + (lane & 15)) * 32 + kg];
      #pragma unroll
      for (int mf = 0; mf < 4; ++mf)
        #pragma unroll
        for (int nf = 0; nf < 4; ++nf)
          acc[mf][nf] = mfma16(aF[mf], bF[nf], acc[mf][nf]);
    }
    if (kk < 3) __syncthreads();
  }

  int orow0 = mtile * 128 + wr * 64 + (lane >> 4) * 4;
  #pragma unroll
  for (int nf = 0; nf < 4; ++nf) {
    int col = ctile * 128 + wc * 64 + nf * 16 + (lane & 15);
    float bo = bias[col];
    #pragma unroll
    for (int mf = 0; mf < 4; ++mf) {
      #pragma unroll
      for (int r = 0; r < 4; ++r) {
        int row = orow0 + mf * 16 + r;
        out[(size_t)row * 256 + col] = acc[mf][nf][r] + bo;
      }
    }
  }
}

// ---------------- host ----------------
extern "C" void kernel_launch(void* const* d_in, const int* in_sizes, int n_in,
                              void* d_out, int out_size, void* d_ws, size_t ws_size,
                              hipStream_t stream)
{
  const float* x    = (const float*)d_in[0];
  const float* Win  = (const float*)d_in[1];
  const float* bin  = (const float*)d_in[2];
  const float* Wout = (const float*)d_in[3];
  const float* bout = (const float*)d_in[4];
  float* out = (float*)d_out;
  char* ws = (char*)d_ws;

  // ws layout: Wt_in (256 KiB) | Wt_out (128 KiB) | yb (64 MiB)
  unsigned short* wtin  = (unsigned short*)(ws);
  unsigned short* wtout = (unsigned short*)(ws + 262144);
  unsigned short* yb    = (unsigned short*)(ws + 393216);

  cvtW_k<<<768, 256, 0, stream>>>(Win, Wout, wtin, wtout);
  g1scan_k<<<512, 512, 0, stream>>>(x, wtin, bin, yb);
  gemm2_k<<<2048, 256, 0, stream>>>(yb, wtout, bout, out);
}

// Round 18
// 178.473 us; speedup vs baseline: 1.1383x; 1.1111x over previous
//
#include <hip/hip_runtime.h>
#include <hip/hip_bf16.h>
#include <hip/hip_fp16.h>
#include <cstdint>

typedef __attribute__((ext_vector_type(4))) float f32x4;
typedef __attribute__((ext_vector_type(8))) short s16x8;

#define DEVI static __device__ __forceinline__

constexpr int Bc = 8, Tc = 2048, Sc = 8, Dc = 256;
constexpr int Mc = Bc * Tc * Sc;  // 131072 rows

// plain-cast f32->bf16 (RNE): compiler packs pairs into v_cvt_pk_bf16_f32
DEVI unsigned short f2bf(float x) {
  return __bfloat16_as_ushort(__float2bfloat16(x));
}

DEVI f32x4 mfma16(s16x8 a, s16x8 b, f32x4 c) {
  return __builtin_amdgcn_mfma_f32_16x16x32_bf16(a, b, c, 0, 0, 0);
}

// async global->LDS, 16B per lane (dest must be wave-uniform base + lane*16)
DEVI void gld16(const void* g, void* l) {
  __builtin_amdgcn_global_load_lds(
      (const __attribute__((address_space(1))) unsigned int*)g,
      (__attribute__((address_space(3))) unsigned int*)l, 16, 0, 0);
}

// ---------------- x f32 -> bf16 (at HBM roofline, ~30us) ----------------
__global__ void cvt_x_k(const float* __restrict__ in, unsigned short* __restrict__ out, int n) {
  int i = (blockIdx.x * blockDim.x + threadIdx.x) * 8;
  int stride = gridDim.x * blockDim.x * 8;
  for (; i < n; i += stride) {
    f32x4 a = *(const f32x4*)(in + i);
    f32x4 b = *(const f32x4*)(in + i + 4);
    s16x8 o;
    o[0] = (short)f2bf(a[0]); o[1] = (short)f2bf(a[1]);
    o[2] = (short)f2bf(a[2]); o[3] = (short)f2bf(a[3]);
    o[4] = (short)f2bf(b[0]); o[5] = (short)f2bf(b[1]);
    o[6] = (short)f2bf(b[2]); o[7] = (short)f2bf(b[3]);
    *(s16x8*)(out + i) = o;
  }
}

// ---------------- weight transpose+convert (both W in one kernel) ----------------
__global__ void cvtW_k(const float* __restrict__ Win, const float* __restrict__ Wout,
                       unsigned short* __restrict__ wtin, unsigned short* __restrict__ wtout) {
  int tid = blockIdx.x * blockDim.x + threadIdx.x;
  if (tid < 512 * 256) {
    int c = tid >> 8, r = tid & 255;
    wtin[tid] = f2bf(Win[r * 512 + c]);
  } else {
    int t = tid - 512 * 256;
    int c = t >> 8, r = t & 255;
    wtout[t] = f2bf(Wout[r * 256 + c]);
  }
}

// ---------------- fused GEMM1 + activation + scan (r15 known-good, 77us) ----------------
// grid 512 = (b,s,dq8), 512 threads = 4 rg x 2 cg; one barrier/chunk; scan via
// per-thread compose + __shfl_up in-wave prefix + 1KB seg walk; rcp activation.
__global__ __launch_bounds__(512, 2) void g1scan_k(
    const unsigned short* __restrict__ xb,   // [M][256] bf16
    const unsigned short* __restrict__ wt,   // [512][256] bf16 = W_in^T
    const float* __restrict__ bias,          // [512]
    unsigned short* __restrict__ yb)         // [M][256] bf16
{
  __shared__ unsigned short As[2][8 * 64 * 32];   // 2 x 32 KB; [buf][kf][row64][32]
  __shared__ float segA[2][4][32], segB[2][4][32]; // 2 KB wave-segment pairs

  int bid = blockIdx.x;
  int lb = (bid & 7) * 64 + (bid >> 3);           // XCD x owns batch b = x
  int b = lb >> 6, s = (lb >> 3) & 7, dq = lb & 7;
  int tid = threadIdx.x;
  int lane = tid & 63, wave = tid >> 6;
  int rg = wave >> 1, cg = wave & 1;              // 4 t-row groups x 2 col groups
  int lo = lane & 15, hi = lane >> 4;

  const short* xs = (const short*)xb;
  const short* wsrc = (const short*)wt;
  size_t rowbase = (size_t)b * 16384 + s;         // global row = rowbase + t*8

  int cl = cg * 16 + lo;                          // d-local col in [0,32)
  int kg = hi * 8;

  // ---- W fragments: global -> registers (one-time, L2-resident weights) ----
  s16x8 bGr[8], bCr[8];
  #pragma unroll
  for (int kf = 0; kf < 8; ++kf) {
    bGr[kf] = *(const s16x8*)(wsrc + (size_t)(dq * 32 + cl) * 256 + kf * 32 + kg);
    bCr[kf] = *(const s16x8*)(wsrc + (size_t)(256 + dq * 32 + cl) * 256 + kf * 32 + kg);
  }
  float bg = bias[dq * 32 + cl];
  float bc = bias[256 + dq * 32 + cl];

  // ---- incremental A-staging pointers: 2048 16B chunks/tile, 4 per thread ----
  const short* pA[4];
  int ldso[4];
  #pragma unroll
  for (int q = 0; q < 4; ++q) {
    int j = q * 512 + tid;
    int kf = j >> 8, rem = j & 255, r = rem >> 2, cc = j & 3;
    pA[q] = xs + (rowbase + (size_t)r * 8) * 256 + kf * 32 + cc * 8;
    ldso[q] = j * 8;
  }
  const size_t ASTRIDE = (size_t)64 * 8 * 256;    // shorts per 64-t chunk

  // prologue: stage chunks 0 and 1
  #pragma unroll
  for (int q = 0; q < 4; ++q) gld16(pA[q], (unsigned short*)As[0] + ldso[q]);
  #pragma unroll
  for (int q = 0; q < 4; ++q) gld16(pA[q] + ASTRIDE, (unsigned short*)As[1] + ldso[q]);
  #pragma unroll
  for (int q = 0; q < 4; ++q) pA[q] += 2 * ASTRIDE;

  float stt = 0.f;   // block scan carry (identical across all threads of same d)

  __syncthreads();   // drains prologue stages

  for (int ch = 0; ch < 32; ++ch) {
    int cur = ch & 1;
    const unsigned short* Ab = (const unsigned short*)As[cur];

    // ---- GEMM: this thread ends with t = ch*64 + rg*16 + hi*4 + [0,4), d = cl ----
    f32x4 accG = {}, accC = {};
    #pragma unroll
    for (int kf = 0; kf < 8; ++kf) {
      s16x8 aF = *(const s16x8*)(Ab + kf * 2048 + (rg * 16 + lo) * 32 + kg);
      accG = mfma16(aF, bGr[kf], accG);
      accC = mfma16(aF, bCr[kf], accC);
    }

    // ---- activation in-register: v_rcp instead of full-precision div ----
    float av[4], bv[4];
    #pragma unroll
    for (int r = 0; r < 4; ++r) {
      float g = accG[r] + bg;
      float c = accC[r] + bc;
      float eg = __expf(-g);
      float alpha = __builtin_amdgcn_rcpf(1.f + eg);
      float e2 = __expf(2.f * c);
      float th = 1.f - 2.f * __builtin_amdgcn_rcpf(e2 + 1.f);  // tanh(c)
      av[r] = 1.f - alpha;
      bv[r] = alpha * th;
    }

    // ---- per-thread compose over its 4 t-steps ----
    float iA = av[0], iB = bv[0];
    #pragma unroll
    for (int r = 1; r < 4; ++r) { iA = iA * av[r]; iB = fmaf(av[r], iB, bv[r]); }

    // ---- in-wave inclusive prefix over hi (4 groups) ----
    {
      float tA = __shfl_up(iA, 16), tB = __shfl_up(iB, 16);
      float nA = tA * iA, nB = fmaf(iA, tB, iB);
      if (hi >= 1) { iA = nA; iB = nB; }
      tA = __shfl_up(iA, 32); tB = __shfl_up(iB, 32);
      nA = tA * iA; nB = fmaf(iA, tB, iB);
      if (hi >= 2) { iA = nA; iB = nB; }
    }
    float eA = __shfl_up(iA, 16), eB = __shfl_up(iB, 16);
    if (hi == 0) { eA = 1.f; eB = 0.f; }
    if (hi == 3) { segA[cur][rg][cl] = iA; segB[cur][rg][cl] = iB; }

    __syncthreads();   // THE barrier: As dbuf + segs + drains stage(ch+1)

    // ---- issue chunk ch+2 staging into the just-freed buffer ----
    if (ch + 2 < 32) {
      #pragma unroll
      for (int q = 0; q < 4; ++q) gld16(pA[q], (unsigned short*)As[cur] + ldso[q]);
      #pragma unroll
      for (int q = 0; q < 4; ++q) pA[q] += ASTRIDE;
    }

    // ---- cross-wave walk over 4 rg segments (redundant, identical per d) ----
    float run = stt, s_w = stt;
    #pragma unroll
    for (int r2 = 0; r2 < 4; ++r2) {
      if (r2 == rg) s_w = run;
      run = fmaf(segA[cur][r2][cl], run, segB[cur][r2][cl]);
    }
    stt = run;                            // carry into next chunk

    // ---- apply: start = excl-wave o carry, then own 4 steps + store ----
    float sv = fmaf(eA, s_w, eB);
    size_t ybase = (rowbase + (size_t)(ch * 64 + rg * 16 + hi * 4) * 8) * 256 + dq * 32 + cl;
    #pragma unroll
    for (int u = 0; u < 4; ++u) {
      sv = fmaf(av[u], sv, bv[u]);
      yb[ybase + (size_t)u * 8 * 256] = f2bf(sv);
    }
  }
}

// ---------------- GEMM2: out = y@W_out + b_out ----------------
// m97-proven shape: 128x128 tile, BK=32, 32KB LDS -> 4 blocks/CU at
// __launch_bounds__(256,4) (r15 used BK=64/64KB/(256,2) = only 2 blocks/CU;
// more co-resident blocks hide the per-iter barrier drains).
__global__ __launch_bounds__(256, 4) void gemm2_k(
    const unsigned short* __restrict__ yb,   // [M][256] bf16
    const unsigned short* __restrict__ wt,   // [256][256] bf16 = W_out^T
    const float* __restrict__ bias,          // [256]
    float* __restrict__ out)
{
  __shared__ unsigned short As[2][128 * 32];
  __shared__ unsigned short Bs[2][128 * 32];

  int bid = blockIdx.x;
  int swz = (bid & 7) * 256 + (bid >> 3);
  int mtile = swz >> 1, ctile = swz & 1;
  int tid = threadIdx.x;
  int lane = tid & 63, wave = tid >> 6;
  int wr = wave >> 1, wc = wave & 1;

  const short* ys = (const short*)yb;
  const short* wsrc = (const short*)wt;

  int srow = tid >> 2, sch = (tid & 3) * 8;
  size_t gArow = (size_t)(mtile * 128 + srow) * 256;
  size_t gBrow = (size_t)(ctile * 128 + srow) * 256;

  auto STAGE = [&](int buf, int k0) {
    gld16(ys + gArow + k0 + sch,                    &As[buf][(size_t)tid * 8]);
    gld16(ys + gArow + (size_t)64 * 256 + k0 + sch, &As[buf][2048 + (size_t)tid * 8]);
    gld16(wsrc + gBrow + k0 + sch,                    &Bs[buf][(size_t)tid * 8]);
    gld16(wsrc + gBrow + (size_t)64 * 256 + k0 + sch, &Bs[buf][2048 + (size_t)tid * 8]);
  };

  f32x4 acc[4][4] = {};

  STAGE(0, 0);
  __syncthreads();
  #pragma unroll
  for (int kk = 0; kk < 8; ++kk) {
    int cur = kk & 1;
    if (kk < 7) STAGE(cur ^ 1, (kk + 1) * 32);
    int kg = (lane >> 4) * 8;
    s16x8 aF[4], bF[4];
    #pragma unroll
    for (int mf = 0; mf < 4; ++mf)
      aF[mf] = *(const s16x8*)&As[cur][(wr * 64 + mf * 16 + (lane & 15)) * 32 + kg];
    #pragma unroll
    for (int nf = 0; nf < 4; ++nf)
      bF[nf] = *(const s16x8*)&Bs[cur][(wc * 64 + nf * 16 + (lane & 15)) * 32 + kg];
    #pragma unroll
    for (int mf = 0; mf < 4; ++mf)
      #pragma unroll
      for (int nf = 0; nf < 4; ++nf)
        acc[mf][nf] = mfma16(aF[mf], bF[nf], acc[mf][nf]);
    __syncthreads();
  }

  int orow0 = mtile * 128 + wr * 64 + (lane >> 4) * 4;
  #pragma unroll
  for (int nf = 0; nf < 4; ++nf) {
    int col = ctile * 128 + wc * 64 + nf * 16 + (lane & 15);
    float bo = bias[col];
    #pragma unroll
    for (int mf = 0; mf < 4; ++mf) {
      #pragma unroll
      for (int r = 0; r < 4; ++r) {
        int row = orow0 + mf * 16 + r;
        out[(size_t)row * 256 + col] = acc[mf][nf][r] + bo;
      }
    }
  }
}

// ---------------- host ----------------
extern "C" void kernel_launch(void* const* d_in, const int* in_sizes, int n_in,
                              void* d_out, int out_size, void* d_ws, size_t ws_size,
                              hipStream_t stream)
{
  const float* x    = (const float*)d_in[0];
  const float* Win  = (const float*)d_in[1];
  const float* bin  = (const float*)d_in[2];
  const float* Wout = (const float*)d_in[3];
  const float* bout = (const float*)d_in[4];
  float* out = (float*)d_out;
  char* ws = (char*)d_ws;

  // ws layout: Wt_in (256 KiB) | Wt_out (128 KiB) | yb (64 MiB) | xb (64 MiB)
  unsigned short* wtin  = (unsigned short*)(ws);
  unsigned short* wtout = (unsigned short*)(ws + 262144);
  unsigned short* yb    = (unsigned short*)(ws + 393216);
  unsigned short* xb    = (unsigned short*)(ws + 393216 + (size_t)Mc * 256 * 2);

  cvt_x_k<<<1024, 256, 0, stream>>>(x, xb, Mc * 256);
  cvtW_k<<<768, 256, 0, stream>>>(Win, Wout, wtin, wtout);
  g1scan_k<<<512, 512, 0, stream>>>(xb, wtin, bin, yb);
  gemm2_k<<<2048, 256, 0, stream>>>(yb, wtout, bout, out);
}

// Round 19
// 157.525 us; speedup vs baseline: 1.2897x; 1.1330x over previous
//
#include <hip/hip_runtime.h>
#include <hip/hip_bf16.h>
#include <hip/hip_fp16.h>
#include <cstdint>

typedef __attribute__((ext_vector_type(4))) float f32x4;
typedef __attribute__((ext_vector_type(8))) short s16x8;

#define DEVI static __device__ __forceinline__

constexpr int Bc = 8, Tc = 2048, Sc = 8, Dc = 256;
constexpr int Mc = Bc * Tc * Sc;  // 131072 rows

// plain-cast f32->bf16 (RNE): compiler packs pairs into v_cvt_pk_bf16_f32
DEVI unsigned short f2bf(float x) {
  return __bfloat16_as_ushort(__float2bfloat16(x));
}

DEVI f32x4 mfma16(s16x8 a, s16x8 b, f32x4 c) {
  return __builtin_amdgcn_mfma_f32_16x16x32_bf16(a, b, c, 0, 0, 0);
}

// async global->LDS, 16B per lane (dest must be wave-uniform base + lane*16)
DEVI void gld16(const void* g, void* l) {
  __builtin_amdgcn_global_load_lds(
      (const __attribute__((address_space(1))) unsigned int*)g,
      (__attribute__((address_space(3))) unsigned int*)l, 16, 0, 0);
}

// ---------------- x f32 -> bf16 (at HBM roofline, ~30us) ----------------
__global__ void cvt_x_k(const float* __restrict__ in, unsigned short* __restrict__ out, int n) {
  int i = (blockIdx.x * blockDim.x + threadIdx.x) * 8;
  int stride = gridDim.x * blockDim.x * 8;
  for (; i < n; i += stride) {
    f32x4 a = *(const f32x4*)(in + i);
    f32x4 b = *(const f32x4*)(in + i + 4);
    s16x8 o;
    o[0] = (short)f2bf(a[0]); o[1] = (short)f2bf(a[1]);
    o[2] = (short)f2bf(a[2]); o[3] = (short)f2bf(a[3]);
    o[4] = (short)f2bf(b[0]); o[5] = (short)f2bf(b[1]);
    o[6] = (short)f2bf(b[2]); o[7] = (short)f2bf(b[3]);
    *(s16x8*)(out + i) = o;
  }
}

// ---------------- weight transpose+convert (both W in one kernel) ----------------
__global__ void cvtW_k(const float* __restrict__ Win, const float* __restrict__ Wout,
                       unsigned short* __restrict__ wtin, unsigned short* __restrict__ wtout) {
  int tid = blockIdx.x * blockDim.x + threadIdx.x;
  if (tid < 512 * 256) {
    int c = tid >> 8, r = tid & 255;
    wtin[tid] = f2bf(Win[r * 512 + c]);
  } else {
    int t = tid - 512 * 256;
    int c = t >> 8, r = t & 255;
    wtout[t] = f2bf(Wout[r * 256 + c]);
  }
}

// ---------------- fused GEMM1 + activation + scan (r15 known-good, 77us) ----------------
__global__ __launch_bounds__(512, 2) void g1scan_k(
    const unsigned short* __restrict__ xb,   // [M][256] bf16
    const unsigned short* __restrict__ wt,   // [512][256] bf16 = W_in^T
    const float* __restrict__ bias,          // [512]
    unsigned short* __restrict__ yb)         // [M][256] bf16
{
  __shared__ unsigned short As[2][8 * 64 * 32];   // 2 x 32 KB; [buf][kf][row64][32]
  __shared__ float segA[2][4][32], segB[2][4][32]; // 2 KB wave-segment pairs

  int bid = blockIdx.x;
  int lb = (bid & 7) * 64 + (bid >> 3);           // XCD x owns batch b = x
  int b = lb >> 6, s = (lb >> 3) & 7, dq = lb & 7;
  int tid = threadIdx.x;
  int lane = tid & 63, wave = tid >> 6;
  int rg = wave >> 1, cg = wave & 1;              // 4 t-row groups x 2 col groups
  int lo = lane & 15, hi = lane >> 4;

  const short* xs = (const short*)xb;
  const short* wsrc = (const short*)wt;
  size_t rowbase = (size_t)b * 16384 + s;         // global row = rowbase + t*8

  int cl = cg * 16 + lo;                          // d-local col in [0,32)
  int kg = hi * 8;

  s16x8 bGr[8], bCr[8];
  #pragma unroll
  for (int kf = 0; kf < 8; ++kf) {
    bGr[kf] = *(const s16x8*)(wsrc + (size_t)(dq * 32 + cl) * 256 + kf * 32 + kg);
    bCr[kf] = *(const s16x8*)(wsrc + (size_t)(256 + dq * 32 + cl) * 256 + kf * 32 + kg);
  }
  float bg = bias[dq * 32 + cl];
  float bc = bias[256 + dq * 32 + cl];

  const short* pA[4];
  int ldso[4];
  #pragma unroll
  for (int q = 0; q < 4; ++q) {
    int j = q * 512 + tid;
    int kf = j >> 8, rem = j & 255, r = rem >> 2, cc = j & 3;
    pA[q] = xs + (rowbase + (size_t)r * 8) * 256 + kf * 32 + cc * 8;
    ldso[q] = j * 8;
  }
  const size_t ASTRIDE = (size_t)64 * 8 * 256;    // shorts per 64-t chunk

  #pragma unroll
  for (int q = 0; q < 4; ++q) gld16(pA[q], (unsigned short*)As[0] + ldso[q]);
  #pragma unroll
  for (int q = 0; q < 4; ++q) gld16(pA[q] + ASTRIDE, (unsigned short*)As[1] + ldso[q]);
  #pragma unroll
  for (int q = 0; q < 4; ++q) pA[q] += 2 * ASTRIDE;

  float stt = 0.f;   // block scan carry (identical across all threads of same d)

  __syncthreads();   // drains prologue stages

  for (int ch = 0; ch < 32; ++ch) {
    int cur = ch & 1;
    const unsigned short* Ab = (const unsigned short*)As[cur];

    f32x4 accG = {}, accC = {};
    #pragma unroll
    for (int kf = 0; kf < 8; ++kf) {
      s16x8 aF = *(const s16x8*)(Ab + kf * 2048 + (rg * 16 + lo) * 32 + kg);
      accG = mfma16(aF, bGr[kf], accG);
      accC = mfma16(aF, bCr[kf], accC);
    }

    float av[4], bv[4];
    #pragma unroll
    for (int r = 0; r < 4; ++r) {
      float g = accG[r] + bg;
      float c = accC[r] + bc;
      float eg = __expf(-g);
      float alpha = __builtin_amdgcn_rcpf(1.f + eg);
      float e2 = __expf(2.f * c);
      float th = 1.f - 2.f * __builtin_amdgcn_rcpf(e2 + 1.f);  // tanh(c)
      av[r] = 1.f - alpha;
      bv[r] = alpha * th;
    }

    float iA = av[0], iB = bv[0];
    #pragma unroll
    for (int r = 1; r < 4; ++r) { iA = iA * av[r]; iB = fmaf(av[r], iB, bv[r]); }

    {
      float tA = __shfl_up(iA, 16), tB = __shfl_up(iB, 16);
      float nA = tA * iA, nB = fmaf(iA, tB, iB);
      if (hi >= 1) { iA = nA; iB = nB; }
      tA = __shfl_up(iA, 32); tB = __shfl_up(iB, 32);
      nA = tA * iA; nB = fmaf(iA, tB, iB);
      if (hi >= 2) { iA = nA; iB = nB; }
    }
    float eA = __shfl_up(iA, 16), eB = __shfl_up(iB, 16);
    if (hi == 0) { eA = 1.f; eB = 0.f; }
    if (hi == 3) { segA[cur][rg][cl] = iA; segB[cur][rg][cl] = iB; }

    __syncthreads();   // THE barrier: As dbuf + segs + drains stage(ch+1)

    if (ch + 2 < 32) {
      #pragma unroll
      for (int q = 0; q < 4; ++q) gld16(pA[q], (unsigned short*)As[cur] + ldso[q]);
      #pragma unroll
      for (int q = 0; q < 4; ++q) pA[q] += ASTRIDE;
    }

    float run = stt, s_w = stt;
    #pragma unroll
    for (int r2 = 0; r2 < 4; ++r2) {
      if (r2 == rg) s_w = run;
      run = fmaf(segA[cur][r2][cl], run, segB[cur][r2][cl]);
    }
    stt = run;                            // carry into next chunk

    float sv = fmaf(eA, s_w, eB);
    size_t ybase = (rowbase + (size_t)(ch * 64 + rg * 16 + hi * 4) * 8) * 256 + dq * 32 + cl;
    #pragma unroll
    for (int u = 0; u < 4; ++u) {
      sv = fmaf(av[u], sv, bv[u]);
      yb[ybase + (size_t)u * 8 * 256] = f2bf(sv);
    }
  }
}

// ---------------- GEMM2: out = y@W_out + b_out ----------------
// FULL-N tile: 128 rows x 256 cols (y read ONCE -> traffic 192MB vs 256MB),
// 512 threads = 8 waves (2 wr x 4 wc, 64x64 out each), BK=64 (proven iter
// count: r2/r18 showed BK=32's 8 barrier-drains regress this kernel).
// LDS 96KB -> 1 block/CU; bandwidth-bound, deep gld16 queues saturate HBM.
// grid 1024 mtiles, XCD-chunked.
__global__ __launch_bounds__(512, 2) void gemm2_k(
    const unsigned short* __restrict__ yb,   // [M][256] bf16
    const unsigned short* __restrict__ wt,   // [256][256] bf16 = W_out^T
    const float* __restrict__ bias,          // [256]
    float* __restrict__ out)
{
  __shared__ unsigned short As[2][2][128 * 32];   // 32 KB  [buf][ksub][row*32+k]
  __shared__ unsigned short Bs[2][2][256 * 32];   // 64 KB

  int bid = blockIdx.x;
  int mtile = (bid & 7) * 128 + (bid >> 3);       // XCD-chunked over 1024 mtiles
  int tid = threadIdx.x;
  int lane = tid & 63, wave = tid >> 6;
  int wr = wave >> 2, wc = wave & 3;              // 2 row-groups x 4 col-groups
  int lo = lane & 15, hi = lane >> 4;
  int kg = hi * 8;

  const short* ys = (const short*)yb;
  const short* wsrc = (const short*)wt;

  auto STAGE = [&](int buf, int k0) {
    // A: 128x64 bf16 = 1024 x 16B chunks; j -> p=j>>9, r=(j>>2)&127, cc=j&3
    #pragma unroll
    for (int q = 0; q < 2; ++q) {
      int j = q * 512 + tid;
      int p = j >> 9, rem = j & 511, r = rem >> 2, cc = rem & 3;
      gld16(ys + (size_t)(mtile * 128 + r) * 256 + k0 + p * 32 + cc * 8,
            &As[buf][0][0] + (size_t)j * 8);
    }
    // B: 256x64 bf16 = 2048 x 16B chunks; j -> p=j>>10, r=(j>>2)&255, cc=j&3
    #pragma unroll
    for (int q = 0; q < 4; ++q) {
      int j = q * 512 + tid;
      int p = j >> 10, rem = j & 1023, r = rem >> 2, cc = rem & 3;
      gld16(wsrc + (size_t)r * 256 + k0 + p * 32 + cc * 8,
            &Bs[buf][0][0] + (size_t)j * 8);
    }
  };

  f32x4 acc[4][4] = {};

  STAGE(0, 0);
  __syncthreads();
  #pragma unroll
  for (int kk = 0; kk < 4; ++kk) {
    int cur = kk & 1;
    if (kk < 3) STAGE(cur ^ 1, (kk + 1) * 64);
    #pragma unroll
    for (int ks = 0; ks < 2; ++ks) {
      s16x8 aF[4], bF[4];
      #pragma unroll
      for (int mf = 0; mf < 4; ++mf)
        aF[mf] = *(const s16x8*)&As[cur][ks][(wr * 64 + mf * 16 + lo) * 32 + kg];
      #pragma unroll
      for (int nf = 0; nf < 4; ++nf)
        bF[nf] = *(const s16x8*)&Bs[cur][ks][(wc * 64 + nf * 16 + lo) * 32 + kg];
      #pragma unroll
      for (int mf = 0; mf < 4; ++mf)
        #pragma unroll
        for (int nf = 0; nf < 4; ++nf)
          acc[mf][nf] = mfma16(aF[mf], bF[nf], acc[mf][nf]);
    }
    if (kk < 3) __syncthreads();
  }

  int orow0 = mtile * 128 + wr * 64 + hi * 4;
  #pragma unroll
  for (int nf = 0; nf < 4; ++nf) {
    int col = wc * 64 + nf * 16 + lo;
    float bo = bias[col];
    #pragma unroll
    for (int mf = 0; mf < 4; ++mf) {
      #pragma unroll
      for (int r = 0; r < 4; ++r) {
        int row = orow0 + mf * 16 + r;
        out[(size_t)row * 256 + col] = acc[mf][nf][r] + bo;
      }
    }
  }
}

// ---------------- host ----------------
extern "C" void kernel_launch(void* const* d_in, const int* in_sizes, int n_in,
                              void* d_out, int out_size, void* d_ws, size_t ws_size,
                              hipStream_t stream)
{
  const float* x    = (const float*)d_in[0];
  const float* Win  = (const float*)d_in[1];
  const float* bin  = (const float*)d_in[2];
  const float* Wout = (const float*)d_in[3];
  const float* bout = (const float*)d_in[4];
  float* out = (float*)d_out;
  char* ws = (char*)d_ws;

  // ws layout: Wt_in (256 KiB) | Wt_out (128 KiB) | yb (64 MiB) | xb (64 MiB)
  unsigned short* wtin  = (unsigned short*)(ws);
  unsigned short* wtout = (unsigned short*)(ws + 262144);
  unsigned short* yb    = (unsigned short*)(ws + 393216);
  unsigned short* xb    = (unsigned short*)(ws + 393216 + (size_t)Mc * 256 * 2);

  cvt_x_k<<<1024, 256, 0, stream>>>(x, xb, Mc * 256);
  cvtW_k<<<768, 256, 0, stream>>>(Win, Wout, wtin, wtout);
  g1scan_k<<<512, 512, 0, stream>>>(xb, wtin, bin, yb);
  gemm2_k<<<1024, 512, 0, stream>>>(yb, wtout, bout, out);
}

// Round 20
// 154.490 us; speedup vs baseline: 1.3150x; 1.0196x over previous
//
#include <hip/hip_runtime.h>
#include <hip/hip_bf16.h>
#include <hip/hip_fp16.h>
#include <cstdint>

typedef __attribute__((ext_vector_type(4))) float f32x4;
typedef __attribute__((ext_vector_type(8))) short s16x8;

#define DEVI static __device__ __forceinline__

constexpr int Bc = 8, Tc = 2048, Sc = 8, Dc = 256;
constexpr int Mc = Bc * Tc * Sc;  // 131072 rows

// plain-cast f32->bf16 (RNE): compiler packs pairs into v_cvt_pk_bf16_f32
DEVI unsigned short f2bf(float x) {
  return __bfloat16_as_ushort(__float2bfloat16(x));
}

DEVI f32x4 mfma16(s16x8 a, s16x8 b, f32x4 c) {
  return __builtin_amdgcn_mfma_f32_16x16x32_bf16(a, b, c, 0, 0, 0);
}

// async global->LDS, 16B per lane (dest must be wave-uniform base + lane*16)
DEVI void gld16(const void* g, void* l) {
  __builtin_amdgcn_global_load_lds(
      (const __attribute__((address_space(1))) unsigned int*)g,
      (__attribute__((address_space(3))) unsigned int*)l, 16, 0, 0);
}

// ---------------- x f32 -> bf16 (at HBM roofline, ~30us) ----------------
__global__ void cvt_x_k(const float* __restrict__ in, unsigned short* __restrict__ out, int n) {
  int i = (blockIdx.x * blockDim.x + threadIdx.x) * 8;
  int stride = gridDim.x * blockDim.x * 8;
  for (; i < n; i += stride) {
    f32x4 a = *(const f32x4*)(in + i);
    f32x4 b = *(const f32x4*)(in + i + 4);
    s16x8 o;
    o[0] = (short)f2bf(a[0]); o[1] = (short)f2bf(a[1]);
    o[2] = (short)f2bf(a[2]); o[3] = (short)f2bf(a[3]);
    o[4] = (short)f2bf(b[0]); o[5] = (short)f2bf(b[1]);
    o[6] = (short)f2bf(b[2]); o[7] = (short)f2bf(b[3]);
    *(s16x8*)(out + i) = o;
  }
}

// ---------------- weight transpose+convert (both W in one kernel) ----------------
__global__ void cvtW_k(const float* __restrict__ Win, const float* __restrict__ Wout,
                       unsigned short* __restrict__ wtin, unsigned short* __restrict__ wtout) {
  int tid = blockIdx.x * blockDim.x + threadIdx.x;
  if (tid < 512 * 256) {
    int c = tid >> 8, r = tid & 255;
    wtin[tid] = f2bf(Win[r * 512 + c]);
  } else {
    int t = tid - 512 * 256;
    int c = t >> 8, r = t & 255;
    wtout[t] = f2bf(Wout[r * 256 + c]);
  }
}

// ---------------- fused GEMM1 + activation + scan (r15 + 2 critical-path trims) ----------------
// grid 512 = (b,s,dq8), 512 threads = 4 rg x 2 cg; one barrier/chunk; scan via
// per-thread compose + __shfl_up in-wave prefix + 1KB seg walk; rcp activation.
// r20 trims: (1) incremental y-store pointer (kills per-chunk 64-bit mul chain
// + per-store addr adds since offsets exceed the 13-bit imm); (2) seg-walk
// loads hoisted to registers before the dependent fmaf chain.
__global__ __launch_bounds__(512, 2) void g1scan_k(
    const unsigned short* __restrict__ xb,   // [M][256] bf16
    const unsigned short* __restrict__ wt,   // [512][256] bf16 = W_in^T
    const float* __restrict__ bias,          // [512]
    unsigned short* __restrict__ yb)         // [M][256] bf16
{
  __shared__ unsigned short As[2][8 * 64 * 32];   // 2 x 32 KB; [buf][kf][row64][32]
  __shared__ float segA[2][4][32], segB[2][4][32]; // 2 KB wave-segment pairs

  int bid = blockIdx.x;
  int lb = (bid & 7) * 64 + (bid >> 3);           // XCD x owns batch b = x
  int b = lb >> 6, s = (lb >> 3) & 7, dq = lb & 7;
  int tid = threadIdx.x;
  int lane = tid & 63, wave = tid >> 6;
  int rg = wave >> 1, cg = wave & 1;              // 4 t-row groups x 2 col groups
  int lo = lane & 15, hi = lane >> 4;

  const short* xs = (const short*)xb;
  const short* wsrc = (const short*)wt;
  size_t rowbase = (size_t)b * 16384 + s;         // global row = rowbase + t*8

  int cl = cg * 16 + lo;                          // d-local col in [0,32)
  int kg = hi * 8;

  // ---- W fragments: global -> registers (one-time, L2-resident weights) ----
  s16x8 bGr[8], bCr[8];
  #pragma unroll
  for (int kf = 0; kf < 8; ++kf) {
    bGr[kf] = *(const s16x8*)(wsrc + (size_t)(dq * 32 + cl) * 256 + kf * 32 + kg);
    bCr[kf] = *(const s16x8*)(wsrc + (size_t)(256 + dq * 32 + cl) * 256 + kf * 32 + kg);
  }
  float bg = bias[dq * 32 + cl];
  float bc = bias[256 + dq * 32 + cl];

  // ---- incremental A-staging pointers: 2048 16B chunks/tile, 4 per thread ----
  const short* pA[4];
  int ldso[4];
  #pragma unroll
  for (int q = 0; q < 4; ++q) {
    int j = q * 512 + tid;
    int kf = j >> 8, rem = j & 255, r = rem >> 2, cc = j & 3;
    pA[q] = xs + (rowbase + (size_t)r * 8) * 256 + kf * 32 + cc * 8;
    ldso[q] = j * 8;
  }
  const size_t ASTRIDE = (size_t)64 * 8 * 256;    // shorts per 64-t chunk

  // ---- incremental y-store pointer (trim #1) ----
  unsigned short* yp = yb + (rowbase + (size_t)(rg * 16 + hi * 4) * 8) * 256 + dq * 32 + cl;
  const size_t YCH = (size_t)64 * 8 * 256;        // shorts per chunk
  const size_t YT  = (size_t)8 * 256;             // shorts per t-step

  // prologue: stage chunks 0 and 1
  #pragma unroll
  for (int q = 0; q < 4; ++q) gld16(pA[q], (unsigned short*)As[0] + ldso[q]);
  #pragma unroll
  for (int q = 0; q < 4; ++q) gld16(pA[q] + ASTRIDE, (unsigned short*)As[1] + ldso[q]);
  #pragma unroll
  for (int q = 0; q < 4; ++q) pA[q] += 2 * ASTRIDE;

  float stt = 0.f;   // block scan carry (identical across all threads of same d)

  __syncthreads();   // drains prologue stages

  for (int ch = 0; ch < 32; ++ch) {
    int cur = ch & 1;
    const unsigned short* Ab = (const unsigned short*)As[cur];

    // ---- GEMM: this thread ends with t = ch*64 + rg*16 + hi*4 + [0,4), d = cl ----
    f32x4 accG = {}, accC = {};
    #pragma unroll
    for (int kf = 0; kf < 8; ++kf) {
      s16x8 aF = *(const s16x8*)(Ab + kf * 2048 + (rg * 16 + lo) * 32 + kg);
      accG = mfma16(aF, bGr[kf], accG);
      accC = mfma16(aF, bCr[kf], accC);
    }

    // ---- activation in-register: v_rcp instead of full-precision div ----
    float av[4], bv[4];
    #pragma unroll
    for (int r = 0; r < 4; ++r) {
      float g = accG[r] + bg;
      float c = accC[r] + bc;
      float eg = __expf(-g);
      float alpha = __builtin_amdgcn_rcpf(1.f + eg);
      float e2 = __expf(2.f * c);
      float th = 1.f - 2.f * __builtin_amdgcn_rcpf(e2 + 1.f);  // tanh(c)
      av[r] = 1.f - alpha;
      bv[r] = alpha * th;
    }

    // ---- per-thread compose over its 4 t-steps ----
    float iA = av[0], iB = bv[0];
    #pragma unroll
    for (int r = 1; r < 4; ++r) { iA = iA * av[r]; iB = fmaf(av[r], iB, bv[r]); }

    // ---- in-wave inclusive prefix over hi (4 groups) ----
    {
      float tA = __shfl_up(iA, 16), tB = __shfl_up(iB, 16);
      float nA = tA * iA, nB = fmaf(iA, tB, iB);
      if (hi >= 1) { iA = nA; iB = nB; }
      tA = __shfl_up(iA, 32); tB = __shfl_up(iB, 32);
      nA = tA * iA; nB = fmaf(iA, tB, iB);
      if (hi >= 2) { iA = nA; iB = nB; }
    }
    float eA = __shfl_up(iA, 16), eB = __shfl_up(iB, 16);
    if (hi == 0) { eA = 1.f; eB = 0.f; }
    if (hi == 3) { segA[cur][rg][cl] = iA; segB[cur][rg][cl] = iB; }

    __syncthreads();   // THE barrier: As dbuf + segs + drains stage(ch+1)

    // ---- issue chunk ch+2 staging into the just-freed buffer ----
    if (ch + 2 < 32) {
      #pragma unroll
      for (int q = 0; q < 4; ++q) gld16(pA[q], (unsigned short*)As[cur] + ldso[q]);
      #pragma unroll
      for (int q = 0; q < 4; ++q) pA[q] += ASTRIDE;
    }

    // ---- cross-wave walk: hoist all 8 seg loads (trim #2), then fmaf chain ----
    float sa[4], sb[4];
    #pragma unroll
    for (int r2 = 0; r2 < 4; ++r2) { sa[r2] = segA[cur][r2][cl]; sb[r2] = segB[cur][r2][cl]; }
    float run = stt, s_w = stt;
    #pragma unroll
    for (int r2 = 0; r2 < 4; ++r2) {
      if (r2 == rg) s_w = run;
      run = fmaf(sa[r2], run, sb[r2]);
    }
    stt = run;                            // carry into next chunk

    // ---- apply: start = excl-wave o carry, then own 4 steps + store ----
    float sv = fmaf(eA, s_w, eB);
    #pragma unroll
    for (int u = 0; u < 4; ++u) {
      sv = fmaf(av[u], sv, bv[u]);
      yp[(size_t)u * YT] = f2bf(sv);
    }
    yp += YCH;
  }
}

// ---------------- GEMM2: out = y@W_out + b_out ----------------
// r15's best-measured shape: BK=64 as two [128][32] sub-panels, 64KB LDS,
// grid 2048 = 1024 mtiles x 2 ctiles. (BK=32/4-blk regressed: r18; full-N
// 128x256 tile measured equal: r19.)
__global__ __launch_bounds__(256, 2) void gemm2_k(
    const unsigned short* __restrict__ yb,   // [M][256] bf16
    const unsigned short* __restrict__ wt,   // [256][256] bf16 = W_out^T
    const float* __restrict__ bias,          // [256]
    float* __restrict__ out)
{
  __shared__ unsigned short As[2][2][128 * 32];
  __shared__ unsigned short Bs[2][2][128 * 32];

  int bid = blockIdx.x;
  int swz = (bid & 7) * 256 + (bid >> 3);
  int mtile = swz >> 1, ctile = swz & 1;
  int tid = threadIdx.x;
  int lane = tid & 63, wave = tid >> 6;
  int wr = wave >> 1, wc = wave & 1;

  const short* ys = (const short*)yb;
  const short* wsrc = (const short*)wt;

  auto STAGE = [&](int buf, int k0) {
    unsigned short* Ad = &As[buf][0][0];
    unsigned short* Bd = &Bs[buf][0][0];
    #pragma unroll
    for (int q = 0; q < 4; ++q) {
      int j = q * 256 + tid;
      int p = j >> 9, r = (j >> 2) & 127, cc = j & 3;
      int koff = k0 + p * 32 + cc * 8;
      gld16(ys + (size_t)(mtile * 128 + r) * 256 + koff, Ad + (size_t)j * 8);
      gld16(wsrc + (size_t)(ctile * 128 + r) * 256 + koff, Bd + (size_t)j * 8);
    }
  };

  f32x4 acc[4][4] = {};

  STAGE(0, 0);
  __syncthreads();
  #pragma unroll
  for (int kk = 0; kk < 4; ++kk) {
    int cur = kk & 1;
    if (kk < 3) STAGE(cur ^ 1, (kk + 1) * 64);
    int kg = (lane >> 4) * 8;
    #pragma unroll
    for (int ks = 0; ks < 2; ++ks) {
      s16x8 aF[4], bF[4];
      #pragma unroll
      for (int mf = 0; mf < 4; ++mf)
        aF[mf] = *(const s16x8*)&As[cur][ks][(wr * 64 + mf * 16 + (lane & 15)) * 32 + kg];
      #pragma unroll
      for (int nf = 0; nf < 4; ++nf)
        bF[nf] = *(const s16x8*)&Bs[cur][ks][(wc * 64 + nf * 16 + (lane & 15)) * 32 + kg];
      #pragma unroll
      for (int mf = 0; mf < 4; ++mf)
        #pragma unroll
        for (int nf = 0; nf < 4; ++nf)
          acc[mf][nf] = mfma16(aF[mf], bF[nf], acc[mf][nf]);
    }
    if (kk < 3) __syncthreads();
  }

  int orow0 = mtile * 128 + wr * 64 + (lane >> 4) * 4;
  #pragma unroll
  for (int nf = 0; nf < 4; ++nf) {
    int col = ctile * 128 + wc * 64 + nf * 16 + (lane & 15);
    float bo = bias[col];
    #pragma unroll
    for (int mf = 0; mf < 4; ++mf) {
      #pragma unroll
      for (int r = 0; r < 4; ++r) {
        int row = orow0 + mf * 16 + r;
        out[(size_t)row * 256 + col] = acc[mf][nf][r] + bo;
      }
    }
  }
}

// ---------------- host ----------------
extern "C" void kernel_launch(void* const* d_in, const int* in_sizes, int n_in,
                              void* d_out, int out_size, void* d_ws, size_t ws_size,
                              hipStream_t stream)
{
  const float* x    = (const float*)d_in[0];
  const float* Win  = (const float*)d_in[1];
  const float* bin  = (const float*)d_in[2];
  const float* Wout = (const float*)d_in[3];
  const float* bout = (const float*)d_in[4];
  float* out = (float*)d_out;
  char* ws = (char*)d_ws;

  // ws layout: Wt_in (256 KiB) | Wt_out (128 KiB) | yb (64 MiB) | xb (64 MiB)
  unsigned short* wtin  = (unsigned short*)(ws);
  unsigned short* wtout = (unsigned short*)(ws + 262144);
  unsigned short* yb    = (unsigned short*)(ws + 393216);
  unsigned short* xb    = (unsigned short*)(ws + 393216 + (size_t)Mc * 256 * 2);

  cvt_x_k<<<1024, 256, 0, stream>>>(x, xb, Mc * 256);
  cvtW_k<<<768, 256, 0, stream>>>(Win, Wout, wtin, wtout);
  g1scan_k<<<512, 512, 0, stream>>>(xb, wtin, bin, yb);
  gemm2_k<<<2048, 256, 0, stream>>>(yb, wtout, bout, out);
}

// Round 21
// 151.926 us; speedup vs baseline: 1.3372x; 1.0169x over previous
//
#include <hip/hip_runtime.h>
#include <hip/hip_bf16.h>
#include <hip/hip_fp16.h>
#include <cstdint>

typedef __attribute__((ext_vector_type(4))) float f32x4;
typedef __attribute__((ext_vector_type(8))) short s16x8;

#define DEVI static __device__ __forceinline__

constexpr int Bc = 8, Tc = 2048, Sc = 8, Dc = 256;
constexpr int Mc = Bc * Tc * Sc;  // 131072 rows

// plain-cast f32->bf16 (RNE): compiler packs pairs into v_cvt_pk_bf16_f32
DEVI unsigned short f2bf(float x) {
  return __bfloat16_as_ushort(__float2bfloat16(x));
}

DEVI f32x4 mfma16(s16x8 a, s16x8 b, f32x4 c) {
  return __builtin_amdgcn_mfma_f32_16x16x32_bf16(a, b, c, 0, 0, 0);
}

// async global->LDS, 16B per lane (dest must be wave-uniform base + lane*16)
DEVI void gld16(const void* g, void* l) {
  __builtin_amdgcn_global_load_lds(
      (const __attribute__((address_space(1))) unsigned int*)g,
      (__attribute__((address_space(3))) unsigned int*)l, 16, 0, 0);
}

// ---------------- x f32 -> bf16 (at HBM roofline, ~30us) ----------------
__global__ void cvt_x_k(const float* __restrict__ in, unsigned short* __restrict__ out, int n) {
  int i = (blockIdx.x * blockDim.x + threadIdx.x) * 8;
  int stride = gridDim.x * blockDim.x * 8;
  for (; i < n; i += stride) {
    f32x4 a = *(const f32x4*)(in + i);
    f32x4 b = *(const f32x4*)(in + i + 4);
    s16x8 o;
    o[0] = (short)f2bf(a[0]); o[1] = (short)f2bf(a[1]);
    o[2] = (short)f2bf(a[2]); o[3] = (short)f2bf(a[3]);
    o[4] = (short)f2bf(b[0]); o[5] = (short)f2bf(b[1]);
    o[6] = (short)f2bf(b[2]); o[7] = (short)f2bf(b[3]);
    *(s16x8*)(out + i) = o;
  }
}

// ---------------- weight transpose+convert (both W in one kernel) ----------------
__global__ void cvtW_k(const float* __restrict__ Win, const float* __restrict__ Wout,
                       unsigned short* __restrict__ wtin, unsigned short* __restrict__ wtout) {
  int tid = blockIdx.x * blockDim.x + threadIdx.x;
  if (tid < 512 * 256) {
    int c = tid >> 8, r = tid & 255;
    wtin[tid] = f2bf(Win[r * 512 + c]);
  } else {
    int t = tid - 512 * 256;
    int c = t >> 8, r = t & 255;
    wtout[t] = f2bf(Wout[r * 256 + c]);
  }
}

// ---------------- fused GEMM1 + activation + scan ----------------
// r20 + `#pragma unroll 2` on the chunk loop: without unrolling, chunk ch+1's
// GEMM (independent: As valid after the shared barrier) is stuck in program
// order behind chunk ch's seg-walk/apply/store dependent chain. Unroll-2 lets
// the scheduler interleave them (MFMA pipe vs VALU+LDS-load) and makes cur
// compile-time (static LDS indexing).
__global__ __launch_bounds__(512, 2) void g1scan_k(
    const unsigned short* __restrict__ xb,   // [M][256] bf16
    const unsigned short* __restrict__ wt,   // [512][256] bf16 = W_in^T
    const float* __restrict__ bias,          // [512]
    unsigned short* __restrict__ yb)         // [M][256] bf16
{
  __shared__ unsigned short As[2][8 * 64 * 32];   // 2 x 32 KB; [buf][kf][row64][32]
  __shared__ float segA[2][4][32], segB[2][4][32]; // 2 KB wave-segment pairs

  int bid = blockIdx.x;
  int lb = (bid & 7) * 64 + (bid >> 3);           // XCD x owns batch b = x
  int b = lb >> 6, s = (lb >> 3) & 7, dq = lb & 7;
  int tid = threadIdx.x;
  int lane = tid & 63, wave = tid >> 6;
  int rg = wave >> 1, cg = wave & 1;              // 4 t-row groups x 2 col groups
  int lo = lane & 15, hi = lane >> 4;

  const short* xs = (const short*)xb;
  const short* wsrc = (const short*)wt;
  size_t rowbase = (size_t)b * 16384 + s;         // global row = rowbase + t*8

  int cl = cg * 16 + lo;                          // d-local col in [0,32)
  int kg = hi * 8;

  // ---- W fragments: global -> registers (one-time, L2-resident weights) ----
  s16x8 bGr[8], bCr[8];
  #pragma unroll
  for (int kf = 0; kf < 8; ++kf) {
    bGr[kf] = *(const s16x8*)(wsrc + (size_t)(dq * 32 + cl) * 256 + kf * 32 + kg);
    bCr[kf] = *(const s16x8*)(wsrc + (size_t)(256 + dq * 32 + cl) * 256 + kf * 32 + kg);
  }
  float bg = bias[dq * 32 + cl];
  float bc = bias[256 + dq * 32 + cl];

  // ---- incremental A-staging pointers: 2048 16B chunks/tile, 4 per thread ----
  const short* pA[4];
  int ldso[4];
  #pragma unroll
  for (int q = 0; q < 4; ++q) {
    int j = q * 512 + tid;
    int kf = j >> 8, rem = j & 255, r = rem >> 2, cc = j & 3;
    pA[q] = xs + (rowbase + (size_t)r * 8) * 256 + kf * 32 + cc * 8;
    ldso[q] = j * 8;
  }
  const size_t ASTRIDE = (size_t)64 * 8 * 256;    // shorts per 64-t chunk

  // ---- incremental y-store pointer ----
  unsigned short* yp = yb + (rowbase + (size_t)(rg * 16 + hi * 4) * 8) * 256 + dq * 32 + cl;
  const size_t YCH = (size_t)64 * 8 * 256;        // shorts per chunk
  const size_t YT  = (size_t)8 * 256;             // shorts per t-step

  // prologue: stage chunks 0 and 1
  #pragma unroll
  for (int q = 0; q < 4; ++q) gld16(pA[q], (unsigned short*)As[0] + ldso[q]);
  #pragma unroll
  for (int q = 0; q < 4; ++q) gld16(pA[q] + ASTRIDE, (unsigned short*)As[1] + ldso[q]);
  #pragma unroll
  for (int q = 0; q < 4; ++q) pA[q] += 2 * ASTRIDE;

  float stt = 0.f;   // block scan carry (identical across all threads of same d)

  __syncthreads();   // drains prologue stages

  #pragma unroll 2
  for (int ch = 0; ch < 32; ++ch) {
    int cur = ch & 1;
    const unsigned short* Ab = (const unsigned short*)As[cur];

    // ---- GEMM: this thread ends with t = ch*64 + rg*16 + hi*4 + [0,4), d = cl ----
    f32x4 accG = {}, accC = {};
    #pragma unroll
    for (int kf = 0; kf < 8; ++kf) {
      s16x8 aF = *(const s16x8*)(Ab + kf * 2048 + (rg * 16 + lo) * 32 + kg);
      accG = mfma16(aF, bGr[kf], accG);
      accC = mfma16(aF, bCr[kf], accC);
    }

    // ---- activation in-register: v_rcp instead of full-precision div ----
    float av[4], bv[4];
    #pragma unroll
    for (int r = 0; r < 4; ++r) {
      float g = accG[r] + bg;
      float c = accC[r] + bc;
      float eg = __expf(-g);
      float alpha = __builtin_amdgcn_rcpf(1.f + eg);
      float e2 = __expf(2.f * c);
      float th = 1.f - 2.f * __builtin_amdgcn_rcpf(e2 + 1.f);  // tanh(c)
      av[r] = 1.f - alpha;
      bv[r] = alpha * th;
    }

    // ---- per-thread compose over its 4 t-steps ----
    float iA = av[0], iB = bv[0];
    #pragma unroll
    for (int r = 1; r < 4; ++r) { iA = iA * av[r]; iB = fmaf(av[r], iB, bv[r]); }

    // ---- in-wave inclusive prefix over hi (4 groups) ----
    {
      float tA = __shfl_up(iA, 16), tB = __shfl_up(iB, 16);
      float nA = tA * iA, nB = fmaf(iA, tB, iB);
      if (hi >= 1) { iA = nA; iB = nB; }
      tA = __shfl_up(iA, 32); tB = __shfl_up(iB, 32);
      nA = tA * iA; nB = fmaf(iA, tB, iB);
      if (hi >= 2) { iA = nA; iB = nB; }
    }
    float eA = __shfl_up(iA, 16), eB = __shfl_up(iB, 16);
    if (hi == 0) { eA = 1.f; eB = 0.f; }
    if (hi == 3) { segA[cur][rg][cl] = iA; segB[cur][rg][cl] = iB; }

    __syncthreads();   // THE barrier: As dbuf + segs + drains stage(ch+1)

    // ---- issue chunk ch+2 staging into the just-freed buffer ----
    if (ch + 2 < 32) {
      #pragma unroll
      for (int q = 0; q < 4; ++q) gld16(pA[q], (unsigned short*)As[cur] + ldso[q]);
      #pragma unroll
      for (int q = 0; q < 4; ++q) pA[q] += ASTRIDE;
    }

    // ---- cross-wave walk: seg loads hoisted, then fmaf chain ----
    float sa[4], sb[4];
    #pragma unroll
    for (int r2 = 0; r2 < 4; ++r2) { sa[r2] = segA[cur][r2][cl]; sb[r2] = segB[cur][r2][cl]; }
    float run = stt, s_w = stt;
    #pragma unroll
    for (int r2 = 0; r2 < 4; ++r2) {
      if (r2 == rg) s_w = run;
      run = fmaf(sa[r2], run, sb[r2]);
    }
    stt = run;                            // carry into next chunk

    // ---- apply: start = excl-wave o carry, then own 4 steps + store ----
    float sv = fmaf(eA, s_w, eB);
    #pragma unroll
    for (int u = 0; u < 4; ++u) {
      sv = fmaf(av[u], sv, bv[u]);
      yp[(size_t)u * YT] = f2bf(sv);
    }
    yp += YCH;
  }
}

// ---------------- GEMM2: out = y@W_out + b_out ----------------
// r15's best-measured shape: BK=64 as two [128][32] sub-panels, 64KB LDS,
// grid 2048 = 1024 mtiles x 2 ctiles. (BK=32/4-blk regressed: r18; full-N
// 128x256 tile measured equal: r19.)
__global__ __launch_bounds__(256, 2) void gemm2_k(
    const unsigned short* __restrict__ yb,   // [M][256] bf16
    const unsigned short* __restrict__ wt,   // [256][256] bf16 = W_out^T
    const float* __restrict__ bias,          // [256]
    float* __restrict__ out)
{
  __shared__ unsigned short As[2][2][128 * 32];
  __shared__ unsigned short Bs[2][2][128 * 32];

  int bid = blockIdx.x;
  int swz = (bid & 7) * 256 + (bid >> 3);
  int mtile = swz >> 1, ctile = swz & 1;
  int tid = threadIdx.x;
  int lane = tid & 63, wave = tid >> 6;
  int wr = wave >> 1, wc = wave & 1;

  const short* ys = (const short*)yb;
  const short* wsrc = (const short*)wt;

  auto STAGE = [&](int buf, int k0) {
    unsigned short* Ad = &As[buf][0][0];
    unsigned short* Bd = &Bs[buf][0][0];
    #pragma unroll
    for (int q = 0; q < 4; ++q) {
      int j = q * 256 + tid;
      int p = j >> 9, r = (j >> 2) & 127, cc = j & 3;
      int koff = k0 + p * 32 + cc * 8;
      gld16(ys + (size_t)(mtile * 128 + r) * 256 + koff, Ad + (size_t)j * 8);
      gld16(wsrc + (size_t)(ctile * 128 + r) * 256 + koff, Bd + (size_t)j * 8);
    }
  };

  f32x4 acc[4][4] = {};

  STAGE(0, 0);
  __syncthreads();
  #pragma unroll
  for (int kk = 0; kk < 4; ++kk) {
    int cur = kk & 1;
    if (kk < 3) STAGE(cur ^ 1, (kk + 1) * 64);
    int kg = (lane >> 4) * 8;
    #pragma unroll
    for (int ks = 0; ks < 2; ++ks) {
      s16x8 aF[4], bF[4];
      #pragma unroll
      for (int mf = 0; mf < 4; ++mf)
        aF[mf] = *(const s16x8*)&As[cur][ks][(wr * 64 + mf * 16 + (lane & 15)) * 32 + kg];
      #pragma unroll
      for (int nf = 0; nf < 4; ++nf)
        bF[nf] = *(const s16x8*)&Bs[cur][ks][(wc * 64 + nf * 16 + (lane & 15)) * 32 + kg];
      #pragma unroll
      for (int mf = 0; mf < 4; ++mf)
        #pragma unroll
        for (int nf = 0; nf < 4; ++nf)
          acc[mf][nf] = mfma16(aF[mf], bF[nf], acc[mf][nf]);
    }
    if (kk < 3) __syncthreads();
  }

  int orow0 = mtile * 128 + wr * 64 + (lane >> 4) * 4;
  #pragma unroll
  for (int nf = 0; nf < 4; ++nf) {
    int col = ctile * 128 + wc * 64 + nf * 16 + (lane & 15);
    float bo = bias[col];
    #pragma unroll
    for (int mf = 0; mf < 4; ++mf) {
      #pragma unroll
      for (int r = 0; r < 4; ++r) {
        int row = orow0 + mf * 16 + r;
        out[(size_t)row * 256 + col] = acc[mf][nf][r] + bo;
      }
    }
  }
}

// ---------------- host ----------------
extern "C" void kernel_launch(void* const* d_in, const int* in_sizes, int n_in,
                              void* d_out, int out_size, void* d_ws, size_t ws_size,
                              hipStream_t stream)
{
  const float* x    = (const float*)d_in[0];
  const float* Win  = (const float*)d_in[1];
  const float* bin  = (const float*)d_in[2];
  const float* Wout = (const float*)d_in[3];
  const float* bout = (const float*)d_in[4];
  float* out = (float*)d_out;
  char* ws = (char*)d_ws;

  // ws layout: Wt_in (256 KiB) | Wt_out (128 KiB) | yb (64 MiB) | xb (64 MiB)
  unsigned short* wtin  = (unsigned short*)(ws);
  unsigned short* wtout = (unsigned short*)(ws + 262144);
  unsigned short* yb    = (unsigned short*)(ws + 393216);
  unsigned short* xb    = (unsigned short*)(ws + 393216 + (size_t)Mc * 256 * 2);

  cvt_x_k<<<1024, 256, 0, stream>>>(x, xb, Mc * 256);
  cvtW_k<<<768, 256, 0, stream>>>(Win, Wout, wtin, wtout);
  g1scan_k<<<512, 512, 0, stream>>>(xb, wtin, bin, yb);
  gemm2_k<<<2048, 256, 0, stream>>>(yb, wtout, bout, out);
}